// Round 23
// baseline (20.878 us; speedup 1.0000x reference)
//
#include <hip/hip_runtime.h>
#include <cstdint>

// Problem constants (from setup_inputs: logits/targets [16,1,512,512] f32)
#define BB 16
#define HH 512
#define WW 512
#define NPIX (BB*HH*WW)          // 4194304
#define WR (HH/32)               // 16 word-rows per image
#define NWORDS (BB*WR*WW)        // 131072 u32 = 512 KB
#define NXCD 8
#define RPB 8                    // rows per block (8-aligned base: p0+7 <= 31)
#define NPAIR (RPB/2)            // 4 row-pairs per block
#define NGRP (BB*HH/RPB)         // 1024 blocks
#define GCHUNK (NGRP/NXCD)       // 128

// ---------------------------------------------------------------------------
// Kernel 0: vertical bit-pack of targets, 4 words per thread via float4 loads.
// vmask[b][w][j] bit r = (targets[b][32w+r][j] > 0.5).  512 KB total.
// ---------------------------------------------------------------------------
__global__ __launch_bounds__(256) void packbits(const float* __restrict__ targets,
                                                uint32_t* __restrict__ vmask) {
    const int flat = blockIdx.x * 256 + threadIdx.x;   // 0..32767
    const int jp = (flat & 127) * 4;                   // 4-aligned column
    const int w  = (flat >> 7) & (WR - 1);
    const int b  = flat >> 11;
    const float4* base =
        (const float4*)(targets + ((size_t)(b * HH + w * 32)) * WW + jp);
    uint32_t w0 = 0, w1 = 0, w2 = 0, w3 = 0;
    #pragma unroll
    for (int r = 0; r < 32; ++r) {
        const float4 q = base[r * (WW / 4)];
        w0 |= (q.x > 0.5f ? 1u : 0u) << r;
        w1 |= (q.y > 0.5f ? 1u : 0u) << r;
        w2 |= (q.z > 0.5f ? 1u : 0u) << r;
        w3 |= (q.w > 0.5f ? 1u : 0u) << r;
    }
    ((uint4*)vmask)[flat] = make_uint4(w0, w1, w2, w3);  // 4*flat == b*8192+w*512+jp
}

// ---------------------------------------------------------------------------
// Fused kernel: one block per 8-ROW GROUP, 512 threads = one column each.
//  Phase 1: transition-mask trick (T = X ^ (X>>1) once per thread); per row
//           dd = ffs(Td>>p), du = clz(Tu<<(32-p))+1; exact word-scan fallback.
//  Phase 2: PAIR-MAJOR LDS uint4 per column; ONE ds_read_b128 per neighbor
//           column serves all 8 rows. k=1..3 branchless (6 b128, k=3 loads
//           issued BEFORE the k=1,2 folds so LDS latency hides under VALU);
//           merged exact tail from k=4 (needs m>16 after k<=3: P ~ 5%/wave).
//  Phase 3: p = clip(sigmoid) via rcp; v += p*sqrt(m); one reduce / 4096 px.
// No atomics/fences (rounds 7/17: all cross-XCD visibility traffic loses).
// ---------------------------------------------------------------------------
__global__ __launch_bounds__(512) void fused_row8(
        const uint32_t* __restrict__ vmask,
        const float* __restrict__ logits,
        float* __restrict__ partial) {
    const int bid = blockIdx.x;
    const int g   = (bid & (NXCD - 1)) * GCHUNK + (bid >> 3);  // bijective swizzle
    const int b   = g >> 6;                 // 64 groups per image
    const int i0  = (g & 63) << 3;          // first row of the group (8-aligned)
    const int j   = threadIdx.x;
    const int w   = i0 >> 5;                // shared word-row (i0..i0+7 same word)
    const int p0  = i0 & 31;                // in {0,8,16,24}

    __shared__ uint4 pk_s[WW];              // 8 KB: [column] -> 4 pair-words
    __shared__ float sw[8];

    const uint32_t* vm = vmask + (size_t)b * WR * WW;

    // one word-column triple serves all 8 rows
    const uint32_t Wse = vm[w * WW + j];
    const bool has_u = (w > 0), has_d = (w < WR - 1);
    const uint32_t Wup = has_u ? vm[(w - 1) * WW + j] : 0u;
    const uint32_t Wdn = has_d ? vm[(w + 1) * WW + j] : 0u;

    // logits for the 8 pixels (independent coalesced loads, overlap phase 1)
    float xs[RPB];
    #pragma unroll
    for (int r = 0; r < RPB; ++r)
        xs[r] = logits[((size_t)(b * HH + i0 + r)) * WW + j];

    // transition masks, once per thread (first transition == first opposite)
    const uint64_t downfull = (uint64_t)Wse | ((uint64_t)Wdn << 32);
    const uint64_t upfull   = ((uint64_t)Wse << 32) | (uint64_t)Wup;
    const uint64_t Td = (downfull ^ (downfull >> 1)) &
                        (has_d ? 0x7FFFFFFFFFFFFFFFull : 0x000000007FFFFFFFull);
    const uint64_t Tu = (upfull ^ (upfull >> 1)) &
                        (has_u ? 0xFFFFFFFFFFFFFFFFull : 0xFFFFFFFF00000000ull);

    int dpx[RPB], tpx[RPB];
    #pragma unroll
    for (int r = 0; r < RPB; ++r) {
        const int p = p0 + r;               // <= 31 always
        const int i = i0 + r;
        const int t = (int)((Wse >> p) & 1u);

        const uint64_t zd = Td >> p;            // transitions at q >= p
        const uint64_t zu = Tu << (32 - p);     // transitions below row i
        int dd, du;
        if (zd) {
            dd = __ffsll((unsigned long long)zd);
        } else {                                // essentially never
            const uint32_t tm = t ? 0xFFFFFFFFu : 0u;
            dd = 1023;
            for (int ww = w + 2; ww < WR; ++ww) {
                const uint32_t Xw = vm[ww * WW + j] ^ tm;
                if (Xw) { dd = 32 * ww + (__ffs(Xw) - 1) - i; break; }
            }
        }
        if (zu) {
            du = __clzll((long long)zu) + 1;
        } else {                                // essentially never
            const uint32_t tm = t ? 0xFFFFFFFFu : 0u;
            du = 1023;
            for (int ww = w - 2; ww >= 0; --ww) {
                const uint32_t Xw = vm[ww * WW + j] ^ tm;
                if (Xw) { du = i - (32 * ww + 31 - __clz((int)Xw)); break; }
            }
        }
        dpx[r] = min(min(dd, du), 1023);
        tpx[r] = t;
    }

    // pack: pair-major uint4 per column, one ds_write_b128
    pk_s[j] = make_uint4(
        (uint32_t)((dpx[0] << 1) | tpx[0]) | ((uint32_t)((dpx[1] << 1) | tpx[1]) << 16),
        (uint32_t)((dpx[2] << 1) | tpx[2]) | ((uint32_t)((dpx[3] << 1) | tpx[3]) << 16),
        (uint32_t)((dpx[4] << 1) | tpx[4]) | ((uint32_t)((dpx[5] << 1) | tpx[5]) << 16),
        (uint32_t)((dpx[6] << 1) | tpx[6]) | ((uint32_t)((dpx[7] << 1) | tpx[7]) << 16));
    __syncthreads();

    // helper: fold one neighbor column (uint4) into all 8 rows' minima
    int mpx[RPB];
    #pragma unroll
    for (int r = 0; r < RPB; ++r) mpx[r] = dpx[r] * dpx[r];

    #define FOLD(COL, K2)                                                        \
        do {                                                                     \
            const uint4 _c = (COL);                                              \
            const uint32_t _w[4] = {_c.x, _c.y, _c.z, _c.w};                     \
            _Pragma("unroll")                                                    \
            for (int _pr = 0; _pr < NPAIR; ++_pr) {                              \
                const uint32_t _pk = _w[_pr];                                    \
                const int _e0 = ((int)(_pk & 1u) == tpx[2 * _pr])                \
                                    ? (int)((_pk & 0xFFFFu) >> 1) : 0;           \
                const int _e1 = ((int)((_pk >> 16) & 1u) == tpx[2 * _pr + 1])    \
                                    ? (int)(_pk >> 17) : 0;                      \
                mpx[2 * _pr]     = min(mpx[2 * _pr],     _e0 * _e0 + (K2));      \
                mpx[2 * _pr + 1] = min(mpx[2 * _pr + 1], _e1 * _e1 + (K2));      \
            }                                                                    \
        } while (0)

    // ---- Phase 2: k=1..3 branchless — issue ALL 6 b128 loads up front so
    //      the k=3 LDS latency hides under the k=1,2 FOLD compute ----
    {
        const int jl1 = j - 1, jr1 = j + 1;
        const int jl2 = j - 2, jr2 = j + 2;
        const int jl3 = j - 3, jr3 = j + 3;
        const uint4 pl1 = pk_s[jl1 >= 0 ? jl1 : 0];
        const uint4 pr1 = pk_s[jr1 < WW ? jr1 : (WW - 1)];
        const uint4 pl2 = pk_s[jl2 >= 0 ? jl2 : 0];
        const uint4 pr2 = pk_s[jr2 < WW ? jr2 : (WW - 1)];
        const uint4 pl3 = pk_s[jl3 >= 0 ? jl3 : 0];
        const uint4 pr3 = pk_s[jr3 < WW ? jr3 : (WW - 1)];
        if (jl1 >= 0) FOLD(pl1, 1);
        if (jr1 < WW) FOLD(pr1, 1);
        if (jl2 >= 0) FOLD(pl2, 4);
        if (jr2 < WW) FOLD(pr2, 4);
        if (jl3 >= 0) FOLD(pl3, 9);
        if (jr3 < WW) FOLD(pr3, 9);
    }

    // ---- merged exact tail from k=4 (needs m>16 after k<=3: ~5%/wave) ----
    {
        int mx = mpx[0];
        #pragma unroll
        for (int r = 1; r < RPB; ++r) mx = max(mx, mpx[r]);
        const int kmaxRow = max(j, WW - 1 - j);
        for (int k = 4; k <= kmaxRow && k * k < mx; ++k) {
            const int k2 = k * k;
            if (k <= j)          FOLD(pk_s[j - k], k2);
            if (k <= WW - 1 - j) FOLD(pk_s[j + k], k2);
            mx = mpx[0];
            #pragma unroll
            for (int r = 1; r < RPB; ++r) mx = max(mx, mpx[r]);
        }
    }
    #undef FOLD

    // ---- Phase 3: loss terms ----
    float v = 0.0f;
    #pragma unroll
    for (int r = 0; r < RPB; ++r) {
        const float dt = __builtin_amdgcn_sqrtf((float)mpx[r]);
        float pr = __builtin_amdgcn_rcpf(1.0f + __expf(-xs[r]));
        pr = fminf(fmaxf(pr, 1e-7f), (float)(1.0 - 1e-7));
        v += pr * dt;
    }

    // ---- block reduction (512 threads = 8 waves), one per 4096 px ----
    #pragma unroll
    for (int off = 32; off > 0; off >>= 1)
        v += __shfl_down(v, off);

    const int lane = threadIdx.x & 63;
    const int wid  = threadIdx.x >> 6;
    if (lane == 0) sw[wid] = v;
    __syncthreads();
    if (threadIdx.x == 0) {
        float s = 0.0f;
        #pragma unroll
        for (int ww = 0; ww < 8; ++ww) s += sw[ww];
        partial[g] = s;
    }
}

// ---------------------------------------------------------------------------
// Deterministic final reduction of NGRP partials -> mean
// ---------------------------------------------------------------------------
__global__ __launch_bounds__(256) void finalreduce(
        const float* __restrict__ partial,
        float* __restrict__ out) {
    const float4 q = ((const float4*)partial)[threadIdx.x];   // 256*4 == 1024
    float v = (q.x + q.y) + (q.z + q.w);

    #pragma unroll
    for (int off = 32; off > 0; off >>= 1)
        v += __shfl_down(v, off);

    __shared__ float sw[4];
    const int lane = threadIdx.x & 63;
    const int wid  = threadIdx.x >> 6;
    if (lane == 0) sw[wid] = v;
    __syncthreads();
    if (threadIdx.x == 0)
        out[0] = ((sw[0] + sw[1]) + (sw[2] + sw[3])) * (1.0f / (float)NPIX);
}

extern "C" void kernel_launch(void* const* d_in, const int* in_sizes, int n_in,
                              void* d_out, int out_size, void* d_ws, size_t ws_size,
                              hipStream_t stream) {
    const float* logits  = (const float*)d_in[0];
    const float* targets = (const float*)d_in[1];
    float* out = (float*)d_out;

    // workspace layout: [ vmask u32 NWORDS (512KB) | partial float NGRP (4KB) ]
    uint32_t* vmask = (uint32_t*)d_ws;
    float* partial  = (float*)((char*)d_ws + (size_t)NWORDS * sizeof(uint32_t));

    packbits<<<NWORDS / 4 / 256, 256, 0, stream>>>(targets, vmask);
    fused_row8<<<NGRP, 512, 0, stream>>>(vmask, logits, partial);
    finalreduce<<<1, 256, 0, stream>>>(partial, out);
}

// Round 24
// 20.236 us; speedup vs baseline: 1.0317x; 1.0317x over previous
//
#include <hip/hip_runtime.h>
#include <cstdint>

// Problem constants (from setup_inputs: logits/targets [16,1,512,512] f32)
#define BB 16
#define HH 512
#define WW 512
#define NPIX (BB*HH*WW)          // 4194304
#define WR (HH/32)               // 16 word-rows per image
#define NWORDS (BB*WR*WW)        // 131072 u32 = 512 KB
#define NXCD 8
#define RPB 8                    // rows per block (8-aligned base: p0+7 <= 31)
#define NPAIR (RPB/2)            // 4 row-pairs per block
#define NGRP (BB*HH/RPB)         // 1024 blocks
#define GCHUNK (NGRP/NXCD)       // 128

// ---------------------------------------------------------------------------
// Kernel 0: vertical bit-pack of targets, 4 words per thread via float4 loads.
// vmask[b][w][j] bit r = (targets[b][32w+r][j] > 0.5).  512 KB total.
// ---------------------------------------------------------------------------
__global__ __launch_bounds__(256) void packbits(const float* __restrict__ targets,
                                                uint32_t* __restrict__ vmask) {
    const int flat = blockIdx.x * 256 + threadIdx.x;   // 0..32767
    const int jp = (flat & 127) * 4;                   // 4-aligned column
    const int w  = (flat >> 7) & (WR - 1);
    const int b  = flat >> 11;
    const float4* base =
        (const float4*)(targets + ((size_t)(b * HH + w * 32)) * WW + jp);
    uint32_t w0 = 0, w1 = 0, w2 = 0, w3 = 0;
    #pragma unroll
    for (int r = 0; r < 32; ++r) {
        const float4 q = base[r * (WW / 4)];
        w0 |= (q.x > 0.5f ? 1u : 0u) << r;
        w1 |= (q.y > 0.5f ? 1u : 0u) << r;
        w2 |= (q.z > 0.5f ? 1u : 0u) << r;
        w3 |= (q.w > 0.5f ? 1u : 0u) << r;
    }
    ((uint4*)vmask)[flat] = make_uint4(w0, w1, w2, w3);  // 4*flat == b*8192+w*512+jp
}

// ---------------------------------------------------------------------------
// Fused kernel: one block per 8-ROW GROUP, 512 threads = one column each.
//  Phase 1: transition-mask trick (T = X ^ (X>>1) once per thread); per row
//           dd = ffs(Td>>p), du = clz(Tu<<(32-p))+1; exact word-scan fallback.
//  Phase 2: PAIR-MAJOR LDS uint4 per column; ONE ds_read_b128 per neighbor
//           column serves all 8 rows. k=1,2 branchless (4 b128); GATED
//           unrolled k=3..5 block only if mx > 9 (exact: k>=3 candidates
//           cost >= 9, cannot improve any row when mx <= 9; round-23 lesson:
//           ungated k=3 hoist taxes all waves and regresses); serial exact
//           tail from k=6 (entered only if mx > 25 after the block, ~1%/wave).
//  Phase 3: p = clip(sigmoid) via rcp; v += p*sqrt(m); one reduce / 4096 px.
// No atomics/fences (rounds 7/17: all cross-XCD visibility traffic loses).
// ---------------------------------------------------------------------------
__global__ __launch_bounds__(512) void fused_row8(
        const uint32_t* __restrict__ vmask,
        const float* __restrict__ logits,
        float* __restrict__ partial) {
    const int bid = blockIdx.x;
    const int g   = (bid & (NXCD - 1)) * GCHUNK + (bid >> 3);  // bijective swizzle
    const int b   = g >> 6;                 // 64 groups per image
    const int i0  = (g & 63) << 3;          // first row of the group (8-aligned)
    const int j   = threadIdx.x;
    const int w   = i0 >> 5;                // shared word-row (i0..i0+7 same word)
    const int p0  = i0 & 31;                // in {0,8,16,24}

    __shared__ uint4 pk_s[WW];              // 8 KB: [column] -> 4 pair-words
    __shared__ float sw[8];

    const uint32_t* vm = vmask + (size_t)b * WR * WW;

    // one word-column triple serves all 8 rows
    const uint32_t Wse = vm[w * WW + j];
    const bool has_u = (w > 0), has_d = (w < WR - 1);
    const uint32_t Wup = has_u ? vm[(w - 1) * WW + j] : 0u;
    const uint32_t Wdn = has_d ? vm[(w + 1) * WW + j] : 0u;

    // logits for the 8 pixels (independent coalesced loads, overlap phase 1)
    float xs[RPB];
    #pragma unroll
    for (int r = 0; r < RPB; ++r)
        xs[r] = logits[((size_t)(b * HH + i0 + r)) * WW + j];

    // transition masks, once per thread (first transition == first opposite)
    const uint64_t downfull = (uint64_t)Wse | ((uint64_t)Wdn << 32);
    const uint64_t upfull   = ((uint64_t)Wse << 32) | (uint64_t)Wup;
    const uint64_t Td = (downfull ^ (downfull >> 1)) &
                        (has_d ? 0x7FFFFFFFFFFFFFFFull : 0x000000007FFFFFFFull);
    const uint64_t Tu = (upfull ^ (upfull >> 1)) &
                        (has_u ? 0xFFFFFFFFFFFFFFFFull : 0xFFFFFFFF00000000ull);

    int dpx[RPB], tpx[RPB];
    #pragma unroll
    for (int r = 0; r < RPB; ++r) {
        const int p = p0 + r;               // <= 31 always
        const int i = i0 + r;
        const int t = (int)((Wse >> p) & 1u);

        const uint64_t zd = Td >> p;            // transitions at q >= p
        const uint64_t zu = Tu << (32 - p);     // transitions below row i
        int dd, du;
        if (zd) {
            dd = __ffsll((unsigned long long)zd);
        } else {                                // essentially never
            const uint32_t tm = t ? 0xFFFFFFFFu : 0u;
            dd = 1023;
            for (int ww = w + 2; ww < WR; ++ww) {
                const uint32_t Xw = vm[ww * WW + j] ^ tm;
                if (Xw) { dd = 32 * ww + (__ffs(Xw) - 1) - i; break; }
            }
        }
        if (zu) {
            du = __clzll((long long)zu) + 1;
        } else {                                // essentially never
            const uint32_t tm = t ? 0xFFFFFFFFu : 0u;
            du = 1023;
            for (int ww = w - 2; ww >= 0; --ww) {
                const uint32_t Xw = vm[ww * WW + j] ^ tm;
                if (Xw) { du = i - (32 * ww + 31 - __clz((int)Xw)); break; }
            }
        }
        dpx[r] = min(min(dd, du), 1023);
        tpx[r] = t;
    }

    // pack: pair-major uint4 per column, one ds_write_b128
    pk_s[j] = make_uint4(
        (uint32_t)((dpx[0] << 1) | tpx[0]) | ((uint32_t)((dpx[1] << 1) | tpx[1]) << 16),
        (uint32_t)((dpx[2] << 1) | tpx[2]) | ((uint32_t)((dpx[3] << 1) | tpx[3]) << 16),
        (uint32_t)((dpx[4] << 1) | tpx[4]) | ((uint32_t)((dpx[5] << 1) | tpx[5]) << 16),
        (uint32_t)((dpx[6] << 1) | tpx[6]) | ((uint32_t)((dpx[7] << 1) | tpx[7]) << 16));
    __syncthreads();

    // helper: fold one neighbor column (uint4) into all 8 rows' minima
    int mpx[RPB];
    #pragma unroll
    for (int r = 0; r < RPB; ++r) mpx[r] = dpx[r] * dpx[r];

    #define FOLD(COL, K2)                                                        \
        do {                                                                     \
            const uint4 _c = (COL);                                              \
            const uint32_t _w[4] = {_c.x, _c.y, _c.z, _c.w};                     \
            _Pragma("unroll")                                                    \
            for (int _pr = 0; _pr < NPAIR; ++_pr) {                              \
                const uint32_t _pk = _w[_pr];                                    \
                const int _e0 = ((int)(_pk & 1u) == tpx[2 * _pr])                \
                                    ? (int)((_pk & 0xFFFFu) >> 1) : 0;           \
                const int _e1 = ((int)((_pk >> 16) & 1u) == tpx[2 * _pr + 1])    \
                                    ? (int)(_pk >> 17) : 0;                      \
                mpx[2 * _pr]     = min(mpx[2 * _pr],     _e0 * _e0 + (K2));      \
                mpx[2 * _pr + 1] = min(mpx[2 * _pr + 1], _e1 * _e1 + (K2));      \
            }                                                                    \
        } while (0)

    // ---- Phase 2: k=1,2 branchless — 4 ds_read_b128 (round-21 proven) ----
    #pragma unroll
    for (int k = 1; k <= 2; ++k) {
        const int jl = j - k, jr = j + k;
        const uint4 pl  = pk_s[jl >= 0 ? jl : 0];
        const uint4 pr_ = pk_s[jr < WW ? jr : (WW - 1)];
        if (jl >= 0) FOLD(pl, k * k);
        if (jr < WW) FOLD(pr_, k * k);
    }

    int mx = mpx[0];
    #pragma unroll
    for (int r = 1; r < RPB; ++r) mx = max(mx, mpx[r]);

    // ---- GATED unrolled k=3..5 (exact gate: k>=3 costs >= 9) ----
    if (mx > 9) {
        const int jl3 = j - 3, jr3 = j + 3;
        const int jl4 = j - 4, jr4 = j + 4;
        const int jl5 = j - 5, jr5 = j + 5;
        const uint4 pl3 = pk_s[jl3 >= 0 ? jl3 : 0];
        const uint4 pr3 = pk_s[jr3 < WW ? jr3 : (WW - 1)];
        const uint4 pl4 = pk_s[jl4 >= 0 ? jl4 : 0];
        const uint4 pr4 = pk_s[jr4 < WW ? jr4 : (WW - 1)];
        const uint4 pl5 = pk_s[jl5 >= 0 ? jl5 : 0];
        const uint4 pr5 = pk_s[jr5 < WW ? jr5 : (WW - 1)];
        if (jl3 >= 0) FOLD(pl3, 9);
        if (jr3 < WW) FOLD(pr3, 9);
        if (jl4 >= 0) FOLD(pl4, 16);
        if (jr4 < WW) FOLD(pr4, 16);
        if (jl5 >= 0) FOLD(pl5, 25);
        if (jr5 < WW) FOLD(pr5, 25);
        mx = mpx[0];
        #pragma unroll
        for (int r = 1; r < RPB; ++r) mx = max(mx, mpx[r]);
    }

    // ---- serial exact tail from k=6 (entered only if mx > 25, ~1%/wave;
    //      correct also when gate skipped: then mx <= 9 < 36 skips this) ----
    {
        const int kmaxRow = max(j, WW - 1 - j);
        for (int k = 6; k <= kmaxRow && k * k < mx; ++k) {
            const int k2 = k * k;
            if (k <= j)          FOLD(pk_s[j - k], k2);
            if (k <= WW - 1 - j) FOLD(pk_s[j + k], k2);
            mx = mpx[0];
            #pragma unroll
            for (int r = 1; r < RPB; ++r) mx = max(mx, mpx[r]);
        }
    }
    #undef FOLD

    // ---- Phase 3: loss terms ----
    float v = 0.0f;
    #pragma unroll
    for (int r = 0; r < RPB; ++r) {
        const float dt = __builtin_amdgcn_sqrtf((float)mpx[r]);
        float pr = __builtin_amdgcn_rcpf(1.0f + __expf(-xs[r]));
        pr = fminf(fmaxf(pr, 1e-7f), (float)(1.0 - 1e-7));
        v += pr * dt;
    }

    // ---- block reduction (512 threads = 8 waves), one per 4096 px ----
    #pragma unroll
    for (int off = 32; off > 0; off >>= 1)
        v += __shfl_down(v, off);

    const int lane = threadIdx.x & 63;
    const int wid  = threadIdx.x >> 6;
    if (lane == 0) sw[wid] = v;
    __syncthreads();
    if (threadIdx.x == 0) {
        float s = 0.0f;
        #pragma unroll
        for (int ww = 0; ww < 8; ++ww) s += sw[ww];
        partial[g] = s;
    }
}

// ---------------------------------------------------------------------------
// Deterministic final reduction of NGRP partials -> mean
// ---------------------------------------------------------------------------
__global__ __launch_bounds__(256) void finalreduce(
        const float* __restrict__ partial,
        float* __restrict__ out) {
    const float4 q = ((const float4*)partial)[threadIdx.x];   // 256*4 == 1024
    float v = (q.x + q.y) + (q.z + q.w);

    #pragma unroll
    for (int off = 32; off > 0; off >>= 1)
        v += __shfl_down(v, off);

    __shared__ float sw[4];
    const int lane = threadIdx.x & 63;
    const int wid  = threadIdx.x >> 6;
    if (lane == 0) sw[wid] = v;
    __syncthreads();
    if (threadIdx.x == 0)
        out[0] = ((sw[0] + sw[1]) + (sw[2] + sw[3])) * (1.0f / (float)NPIX);
}

extern "C" void kernel_launch(void* const* d_in, const int* in_sizes, int n_in,
                              void* d_out, int out_size, void* d_ws, size_t ws_size,
                              hipStream_t stream) {
    const float* logits  = (const float*)d_in[0];
    const float* targets = (const float*)d_in[1];
    float* out = (float*)d_out;

    // workspace layout: [ vmask u32 NWORDS (512KB) | partial float NGRP (4KB) ]
    uint32_t* vmask = (uint32_t*)d_ws;
    float* partial  = (float*)((char*)d_ws + (size_t)NWORDS * sizeof(uint32_t));

    packbits<<<NWORDS / 4 / 256, 256, 0, stream>>>(targets, vmask);
    fused_row8<<<NGRP, 512, 0, stream>>>(vmask, logits, partial);
    finalreduce<<<1, 256, 0, stream>>>(partial, out);
}

// Round 26
// 19.840 us; speedup vs baseline: 1.0524x; 1.0200x over previous
//
#include <hip/hip_runtime.h>
#include <cstdint>

// Problem constants (from setup_inputs: logits/targets [16,1,512,512] f32)
#define BB 16
#define HH 512
#define WW 512
#define NPIX (BB*HH*WW)          // 4194304
#define WR (HH/32)               // 16 word-rows per image
#define NWORDS (BB*WR*WW)        // 131072 u32 = 512 KB
#define NXCD 8
#define RPB 8                    // rows per block (8-aligned base: p0+7 <= 31)
#define NPAIR (RPB/2)            // 4 row-pairs per block
#define NGRP (BB*HH/RPB)         // 1024 blocks
#define GCHUNK (NGRP/NXCD)       // 128

// ---------------------------------------------------------------------------
// FINAL CONFIGURATION (round-21 best: 19.96 us, absmax 0.0).
// Search summary (26 rounds): 69.7 -> 19.96 us (3.5x).
//  - bitmask column search (ffs/clz on 64-bit windows) replaced 13 f32
//    loads/px: 34 -> 28 us
//  - 8-rows-per-block amortization + rcp/sqrt intrinsics: 28 -> 22 us
//  - two-rows-per-LDS-word pair packing (phase 2 is LDS-issue bound):
//    22 -> 20.5 us;  pair-major uint4 + ds_read_b128: -> 19.96 us
// Measured losers (kept out): per-block device fences (+180 us), same-line
// atomics across XCDs (+10 us), ungated deeper unrolls (+0.3..+9 us),
// ring search (+15 us), ballot in-row candidates (+12 us).
// ---------------------------------------------------------------------------

// ---------------------------------------------------------------------------
// Kernel 0: vertical bit-pack of targets, 4 words per thread via float4 loads.
// vmask[b][w][j] bit r = (targets[b][32w+r][j] > 0.5).  512 KB total.
// ---------------------------------------------------------------------------
__global__ __launch_bounds__(256) void packbits(const float* __restrict__ targets,
                                                uint32_t* __restrict__ vmask) {
    const int flat = blockIdx.x * 256 + threadIdx.x;   // 0..32767
    const int jp = (flat & 127) * 4;                   // 4-aligned column
    const int w  = (flat >> 7) & (WR - 1);
    const int b  = flat >> 11;
    const float4* base =
        (const float4*)(targets + ((size_t)(b * HH + w * 32)) * WW + jp);
    uint32_t w0 = 0, w1 = 0, w2 = 0, w3 = 0;
    #pragma unroll
    for (int r = 0; r < 32; ++r) {
        const float4 q = base[r * (WW / 4)];
        w0 |= (q.x > 0.5f ? 1u : 0u) << r;
        w1 |= (q.y > 0.5f ? 1u : 0u) << r;
        w2 |= (q.z > 0.5f ? 1u : 0u) << r;
        w3 |= (q.w > 0.5f ? 1u : 0u) << r;
    }
    ((uint4*)vmask)[flat] = make_uint4(w0, w1, w2, w3);  // 4*flat == b*8192+w*512+jp
}

// ---------------------------------------------------------------------------
// Fused kernel: one block per 8-ROW GROUP, 512 threads = one column each.
//  Phase 1: transition-mask trick (T = X ^ (X>>1) once per thread); per row
//           dd = ffs(Td>>p), du = clz(Tu<<(32-p))+1; exact word-scan fallback.
//  Phase 2: PAIR-MAJOR LDS uint4 per column; ONE ds_read_b128 per neighbor
//           column serves all 8 rows. k=1,2 unroll (4 b128) + merged exact
//           tail while k^2 < max_r m[r] (exact: candidates cost >= k^2).
//  Phase 3: p = clip(sigmoid) via rcp; v += p*sqrt(m); one reduce / 4096 px.
// No atomics/fences (rounds 7/17: all cross-XCD visibility traffic loses).
// ---------------------------------------------------------------------------
__global__ __launch_bounds__(512) void fused_row8(
        const uint32_t* __restrict__ vmask,
        const float* __restrict__ logits,
        float* __restrict__ partial) {
    const int bid = blockIdx.x;
    const int g   = (bid & (NXCD - 1)) * GCHUNK + (bid >> 3);  // bijective swizzle
    const int b   = g >> 6;                 // 64 groups per image
    const int i0  = (g & 63) << 3;          // first row of the group (8-aligned)
    const int j   = threadIdx.x;
    const int w   = i0 >> 5;                // shared word-row (i0..i0+7 same word)
    const int p0  = i0 & 31;                // in {0,8,16,24}

    __shared__ uint4 pk_s[WW];              // 8 KB: [column] -> 4 pair-words
    __shared__ float sw[8];

    const uint32_t* vm = vmask + (size_t)b * WR * WW;

    // one word-column triple serves all 8 rows
    const uint32_t Wse = vm[w * WW + j];
    const bool has_u = (w > 0), has_d = (w < WR - 1);
    const uint32_t Wup = has_u ? vm[(w - 1) * WW + j] : 0u;
    const uint32_t Wdn = has_d ? vm[(w + 1) * WW + j] : 0u;

    // logits for the 8 pixels (independent coalesced loads, overlap phase 1)
    float xs[RPB];
    #pragma unroll
    for (int r = 0; r < RPB; ++r)
        xs[r] = logits[((size_t)(b * HH + i0 + r)) * WW + j];

    // transition masks, once per thread (first transition == first opposite)
    const uint64_t downfull = (uint64_t)Wse | ((uint64_t)Wdn << 32);
    const uint64_t upfull   = ((uint64_t)Wse << 32) | (uint64_t)Wup;
    const uint64_t Td = (downfull ^ (downfull >> 1)) &
                        (has_d ? 0x7FFFFFFFFFFFFFFFull : 0x000000007FFFFFFFull);
    const uint64_t Tu = (upfull ^ (upfull >> 1)) &
                        (has_u ? 0xFFFFFFFFFFFFFFFFull : 0xFFFFFFFF00000000ull);

    int dpx[RPB], tpx[RPB];
    #pragma unroll
    for (int r = 0; r < RPB; ++r) {
        const int p = p0 + r;               // <= 31 always
        const int i = i0 + r;
        const int t = (int)((Wse >> p) & 1u);

        const uint64_t zd = Td >> p;            // transitions at q >= p
        const uint64_t zu = Tu << (32 - p);     // transitions below row i
        int dd, du;
        if (zd) {
            dd = __ffsll((unsigned long long)zd);
        } else {                                // essentially never
            const uint32_t tm = t ? 0xFFFFFFFFu : 0u;
            dd = 1023;
            for (int ww = w + 2; ww < WR; ++ww) {
                const uint32_t Xw = vm[ww * WW + j] ^ tm;
                if (Xw) { dd = 32 * ww + (__ffs(Xw) - 1) - i; break; }
            }
        }
        if (zu) {
            du = __clzll((long long)zu) + 1;
        } else {                                // essentially never
            const uint32_t tm = t ? 0xFFFFFFFFu : 0u;
            du = 1023;
            for (int ww = w - 2; ww >= 0; --ww) {
                const uint32_t Xw = vm[ww * WW + j] ^ tm;
                if (Xw) { du = i - (32 * ww + 31 - __clz((int)Xw)); break; }
            }
        }
        dpx[r] = min(min(dd, du), 1023);
        tpx[r] = t;
    }

    // pack: pair-major uint4 per column, one ds_write_b128
    pk_s[j] = make_uint4(
        (uint32_t)((dpx[0] << 1) | tpx[0]) | ((uint32_t)((dpx[1] << 1) | tpx[1]) << 16),
        (uint32_t)((dpx[2] << 1) | tpx[2]) | ((uint32_t)((dpx[3] << 1) | tpx[3]) << 16),
        (uint32_t)((dpx[4] << 1) | tpx[4]) | ((uint32_t)((dpx[5] << 1) | tpx[5]) << 16),
        (uint32_t)((dpx[6] << 1) | tpx[6]) | ((uint32_t)((dpx[7] << 1) | tpx[7]) << 16));
    __syncthreads();

    // helper: fold one neighbor column (uint4) into all 8 rows' minima
    int mpx[RPB];
    #pragma unroll
    for (int r = 0; r < RPB; ++r) mpx[r] = dpx[r] * dpx[r];

    #define FOLD(COL, K2)                                                        \
        do {                                                                     \
            const uint4 _c = (COL);                                              \
            const uint32_t _w[4] = {_c.x, _c.y, _c.z, _c.w};                     \
            _Pragma("unroll")                                                    \
            for (int _pr = 0; _pr < NPAIR; ++_pr) {                              \
                const uint32_t _pk = _w[_pr];                                    \
                const int _e0 = ((int)(_pk & 1u) == tpx[2 * _pr])                \
                                    ? (int)((_pk & 0xFFFFu) >> 1) : 0;           \
                const int _e1 = ((int)((_pk >> 16) & 1u) == tpx[2 * _pr + 1])    \
                                    ? (int)(_pk >> 17) : 0;                      \
                mpx[2 * _pr]     = min(mpx[2 * _pr],     _e0 * _e0 + (K2));      \
                mpx[2 * _pr + 1] = min(mpx[2 * _pr + 1], _e1 * _e1 + (K2));      \
            }                                                                    \
        } while (0)

    // ---- Phase 2: k=1,2 unrolled — 4 ds_read_b128 total ----
    #pragma unroll
    for (int k = 1; k <= 2; ++k) {
        const int jl = j - k, jr = j + k;
        const uint4 pl  = pk_s[jl >= 0 ? jl : 0];
        const uint4 pr_ = pk_s[jr < WW ? jr : (WW - 1)];
        if (jl >= 0) FOLD(pl, k * k);
        if (jr < WW) FOLD(pr_, k * k);
    }

    // ---- merged exact tail over all 8 rows ----
    {
        int mx = mpx[0];
        #pragma unroll
        for (int r = 1; r < RPB; ++r) mx = max(mx, mpx[r]);
        const int kmaxRow = max(j, WW - 1 - j);
        for (int k = 3; k <= kmaxRow && k * k < mx; ++k) {
            const int k2 = k * k;
            if (k <= j)          FOLD(pk_s[j - k], k2);
            if (k <= WW - 1 - j) FOLD(pk_s[j + k], k2);
            mx = mpx[0];
            #pragma unroll
            for (int r = 1; r < RPB; ++r) mx = max(mx, mpx[r]);
        }
    }
    #undef FOLD

    // ---- Phase 3: loss terms ----
    float v = 0.0f;
    #pragma unroll
    for (int r = 0; r < RPB; ++r) {
        const float dt = __builtin_amdgcn_sqrtf((float)mpx[r]);
        float pr = __builtin_amdgcn_rcpf(1.0f + __expf(-xs[r]));
        pr = fminf(fmaxf(pr, 1e-7f), (float)(1.0 - 1e-7));
        v += pr * dt;
    }

    // ---- block reduction (512 threads = 8 waves), one per 4096 px ----
    #pragma unroll
    for (int off = 32; off > 0; off >>= 1)
        v += __shfl_down(v, off);

    const int lane = threadIdx.x & 63;
    const int wid  = threadIdx.x >> 6;
    if (lane == 0) sw[wid] = v;
    __syncthreads();
    if (threadIdx.x == 0) {
        float s = 0.0f;
        #pragma unroll
        for (int ww = 0; ww < 8; ++ww) s += sw[ww];
        partial[g] = s;
    }
}

// ---------------------------------------------------------------------------
// Deterministic final reduction of NGRP partials -> mean
// ---------------------------------------------------------------------------
__global__ __launch_bounds__(256) void finalreduce(
        const float* __restrict__ partial,
        float* __restrict__ out) {
    const float4 q = ((const float4*)partial)[threadIdx.x];   // 256*4 == 1024
    float v = (q.x + q.y) + (q.z + q.w);

    #pragma unroll
    for (int off = 32; off > 0; off >>= 1)
        v += __shfl_down(v, off);

    __shared__ float sw[4];
    const int lane = threadIdx.x & 63;
    const int wid  = threadIdx.x >> 6;
    if (lane == 0) sw[wid] = v;
    __syncthreads();
    if (threadIdx.x == 0)
        out[0] = ((sw[0] + sw[1]) + (sw[2] + sw[3])) * (1.0f / (float)NPIX);
}

extern "C" void kernel_launch(void* const* d_in, const int* in_sizes, int n_in,
                              void* d_out, int out_size, void* d_ws, size_t ws_size,
                              hipStream_t stream) {
    const float* logits  = (const float*)d_in[0];
    const float* targets = (const float*)d_in[1];
    float* out = (float*)d_out;

    // workspace layout: [ vmask u32 NWORDS (512KB) | partial float NGRP (4KB) ]
    uint32_t* vmask = (uint32_t*)d_ws;
    float* partial  = (float*)((char*)d_ws + (size_t)NWORDS * sizeof(uint32_t));

    packbits<<<NWORDS / 4 / 256, 256, 0, stream>>>(targets, vmask);
    fused_row8<<<NGRP, 512, 0, stream>>>(vmask, logits, partial);
    finalreduce<<<1, 256, 0, stream>>>(partial, out);
}